// Round 4
// baseline (411.786 us; speedup 1.0000x reference)
//
#include <hip/hip_runtime.h>
#include <hip/hip_bf16.h>

// Problem constants (from reference setup_inputs):
//   B=32, T=2000, H=512, L=200, C=40 (39 phones + blank=39)
// Outputs: log_prob (T,B,C) fp32 flat [0, 2560000) then loss scalar at [2560000].

#define BB 32
#define TT 2000
#define HH 512
#define CC 40
#define LL 200
#define NEGV -1e30f

typedef __attribute__((ext_vector_type(8))) short short8;
typedef __attribute__((ext_vector_type(4))) float f32x4;

__device__ __forceinline__ unsigned short f2bf(float f) {
    unsigned u = __float_as_uint(f);
    u = u + 0x7FFFu + ((u >> 16) & 1u);      // RNE truncate to bf16
    return (unsigned short)(u >> 16);
}

// lane i gets lane i-1's value; lane 0 gets 0. VALU DPP (wave_shr:1), no DS.
// PROVEN on gfx950 (round-0 baseline, 395us).
__device__ __forceinline__ double dshr1(double x) {
    int lo = __double2loint(x), hi = __double2hiint(x);
    lo = __builtin_amdgcn_update_dpp(0, lo, 0x138, 0xF, 0xF, false);
    hi = __builtin_amdgcn_update_dpp(0, hi, 0x138, 0xF, 0xF, false);
    return __hiloint2double(hi, lo);
}

// ---------------------------------------------------------------------------
// k0: convert W (C,H) fp32 -> padded bf16 (48,H), classes >= 40 zero.
// ---------------------------------------------------------------------------
__global__ void k0_wconv(const float* __restrict__ W, short* __restrict__ wbf) {
    const int idx = blockIdx.x * 256 + threadIdx.x;
    if (idx < 48 * HH) {
        const int n = idx >> 9, k = idx & (HH - 1);
        wbf[idx] = (n < CC) ? (short)f2bf(W[n * HH + k]) : (short)0;
    }
}

// ---------------------------------------------------------------------------
// k1 (fast): MFMA GEMM + log-softmax. One wave per 16 rows; N=48 (3 tiles),
// K=512 in 16 steps of 32. A: fp32 global -> bf16 in-register. B: bf16 from
// k0's buffer (cache-resident, 48 KB). No LDS, no barriers.
// C/D layout: col=lane&15, row=quad*4+reg. A: row=lane&15, k=quad*8+j.
// Also writes P = exp(log_prob) as (B,T,C): at step t all of k2's lanes then
// read from ONE 160-B row (3 cache lines) instead of 64 scattered rows.
// ---------------------------------------------------------------------------
__global__ __launch_bounds__(256) void k1_mfma(
    const float* __restrict__ hidden,   // (B,T,H)
    const short* __restrict__ wbf,      // (48,H) bf16
    const float* __restrict__ bias,     // (C,)
    float* __restrict__ out,            // (T,B,C)
    float* __restrict__ P)              // (B,T,C) probs
{
    const int tid = threadIdx.x, lane = tid & 63, wv = tid >> 6;
    const int quad = lane >> 4, mcol = lane & 15;
    const int r0 = (blockIdx.x * 4 + wv) * 16;

    const float* aptr = hidden + (size_t)(r0 + mcol) * HH + quad * 8;
    const short* b0p = wbf + (0 * 16 + mcol) * HH + quad * 8;
    const short* b1p = wbf + (1 * 16 + mcol) * HH + quad * 8;
    const short* b2p = wbf + (2 * 16 + mcol) * HH + quad * 8;

    f32x4 acc0 = {0.f, 0.f, 0.f, 0.f};
    f32x4 acc1 = {0.f, 0.f, 0.f, 0.f};
    f32x4 acc2 = {0.f, 0.f, 0.f, 0.f};

    #pragma unroll 2
    for (int kc = 0; kc < 16; ++kc) {
        const float4 al = *(const float4*)(aptr + kc * 32);
        const float4 ah = *(const float4*)(aptr + kc * 32 + 4);
        short8 af;
        af[0] = f2bf(al.x); af[1] = f2bf(al.y); af[2] = f2bf(al.z); af[3] = f2bf(al.w);
        af[4] = f2bf(ah.x); af[5] = f2bf(ah.y); af[6] = f2bf(ah.z); af[7] = f2bf(ah.w);
        const short8 bf0 = *(const short8*)(b0p + kc * 32);
        const short8 bf1 = *(const short8*)(b1p + kc * 32);
        const short8 bf2 = *(const short8*)(b2p + kc * 32);
        acc0 = __builtin_amdgcn_mfma_f32_16x16x32_bf16(af, bf0, acc0, 0, 0, 0);
        acc1 = __builtin_amdgcn_mfma_f32_16x16x32_bf16(af, bf1, acc1, 0, 0, 0);
        acc2 = __builtin_amdgcn_mfma_f32_16x16x32_bf16(af, bf2, acc2, 0, 0, 0);
    }

    // epilogue: bias, row-wise log-softmax over 40 cols (cols 40-47 masked)
    const float bz0 = bias[mcol];
    const float bz1 = bias[16 + mcol];
    const float bz2 = (mcol < 8) ? bias[32 + mcol] : 0.0f;
    float L0[4], L1[4], L2[4], lse[4];
    #pragma unroll
    for (int j = 0; j < 4; ++j) {
        L0[j] = acc0[j] + bz0;
        L1[j] = acc1[j] + bz1;
        L2[j] = (mcol < 8) ? (acc2[j] + bz2) : NEGV;
    }
    #pragma unroll
    for (int j = 0; j < 4; ++j) {
        float m = fmaxf(fmaxf(L0[j], L1[j]), L2[j]);
        #pragma unroll
        for (int o = 1; o < 16; o <<= 1) m = fmaxf(m, __shfl_xor(m, o, 64));
        float s = __expf(L0[j] - m) + __expf(L1[j] - m)
                + ((mcol < 8) ? __expf(L2[j] - m) : 0.0f);
        #pragma unroll
        for (int o = 1; o < 16; o <<= 1) s += __shfl_xor(s, o, 64);
        lse[j] = m + __logf(s);
    }
    #pragma unroll
    for (int j = 0; j < 4; ++j) {
        const int r = r0 + quad * 4 + j;
        const int b = r / TT, t = r - b * TT;
        float* op = out + ((size_t)t * BB + b) * CC;
        float* pp = P + (size_t)r * CC;          // (B,T,C): r = b*TT + t
        const float v0 = L0[j] - lse[j];
        const float v1 = L1[j] - lse[j];
        op[mcol]      = v0;  pp[mcol]      = __expf(v0);
        op[16 + mcol] = v1;  pp[16 + mcol] = __expf(v1);
        if (mcol < 8) {
            const float v2 = L2[j] - lse[j];
            op[32 + mcol] = v2;  pp[32 + mcol] = __expf(v2);
        }
    }
}

// ---------------------------------------------------------------------------
// k2 (fast): CTC alpha recurrence, one wave per batch, 8 states/lane
// (s = 8*lane + i; even i = blank). FP64 linear domain (proven numerics).
// Emissions from P in (B,T,C): per step, all lanes gather 4 class probs from
// ONE 160-B row (~3 cache lines, L1-hot) + a thread-UNIFORM blank load
// (scalarizable to s_load). Row base is uniform (SALU advance); per-lane
// offsets cls[j]*4 are loop-invariant; u*160 folds into the load immediate.
// This replaces the old (B,C,T) per-lane-row gathers that cost 64 cache
// lines PER LOAD INSTRUCTION (the round-3 diagnosis: 85% mem-pipe stall).
// Rescale every 32 steps, lossless pow2 (hi-word int max + exact 2^-ex).
// ---------------------------------------------------------------------------
__global__ __launch_bounds__(64) void k2_fast(
    const float* __restrict__ P,             // (B,T,C) probs
    const int* __restrict__ targets,         // (B,L)
    const int* __restrict__ input_lengths,   // (B,)
    const int* __restrict__ target_lengths,  // (B,)
    float* __restrict__ loss_ws)             // (B,)
{
    const int b = blockIdx.x, l = threadIdx.x;
    const int len = input_lengths[b];
    const int tl  = target_lengths[b];

    // odd states of this lane: s = 8l + 2j+1 -> label index 4l + j
    int cls[4]; double sk[4];
    #pragma unroll
    for (int j = 0; j < 4; ++j) {
        const int idx = 4 * l + j;
        int c = CC - 1; double skv = 0.0;
        if (idx < tl) {
            c = targets[b * LL + idx];
            if (idx == 0) skv = 1.0;   // s==1: a[s-2] is 0; skip=true in ref
            else skv = (c != targets[b * LL + idx - 1]) ? 1.0 : 0.0;
        }
        cls[j] = c; sk[j] = skv;
    }
    const int off0 = cls[0], off1 = cls[1], off2 = cls[2], off3 = cls[3];

    const float* rowb = P + (size_t)b * TT * CC;   // uniform; advances 8 rows/call

    // t = 0 init
    double a0, a1, a2, a3, a4, a5, a6, a7;
    {
        const float pb0 = rowb[CC - 1];
        const float pl0 = rowb[off0];
        a0 = (l == 0) ? (double)pb0 : 0.0;
        a1 = (l == 0) ? (double)pl0 : 0.0;
        a2 = a3 = a4 = a5 = a6 = a7 = 0.0;
    }

    float g0[5][8], g1[5][8];
    auto prefetch = [&](float (&g)[5][8]) {     // loads next 8 t's
        #pragma unroll
        for (int u = 0; u < 8; ++u) {
            const float* row = rowb + u * CC;
            g[0][u] = row[off0];
            g[1][u] = row[off1];
            g[2][u] = row[off2];
            g[3][u] = row[off3];
            g[4][u] = row[CC - 1];               // uniform -> s_load
        }
        rowb += 8 * CC;
    };
    prefetch(g0);                                // t = 0..7 (slot 0 unused)

    double logscale = 0.0;

    auto step = [&](float e1f, float e3f, float e5f, float e7f, float bef) {
        const double be = (double)bef;
        const double p7 = dshr1(a7);             // prev lane's state 8l-1
        const double n0 = (a0 + p7) * be;
        const double n1 = (a1 + fma(sk[0], p7, a0)) * (double)e1f;
        const double n2 = (a2 + a1) * be;
        const double n3 = (a3 + fma(sk[1], a1, a2)) * (double)e3f;
        const double n4 = (a4 + a3) * be;
        const double n5 = (a5 + fma(sk[2], a3, a4)) * (double)e5f;
        const double n6 = (a6 + a5) * be;
        const double n7 = (a7 + fma(sk[3], a5, a6)) * (double)e7f;
        a0 = n0; a1 = n1; a2 = n2; a3 = n3;
        a4 = n4; a5 = n5; a6 = n6; a7 = n7;
    };
    // unconditional 8 steps (whole block known < len) — no per-step cndmask
    auto run8f = [&](const float (&g)[5][8], int ufirst) {
        #pragma unroll
        for (int u = 0; u < 8; ++u)
            if (u >= ufirst)
                step(g[0][u], g[1][u], g[2][u], g[3][u], g[4][u]);
    };
    // checked tail (wave-uniform per-step freeze; dead when len==T)
    auto run8c = [&](const float (&g)[5][8], int tbase, int ufirst) {
        #pragma unroll
        for (int u = 0; u < 8; ++u)
            if (u >= ufirst && tbase + u < len)
                step(g[0][u], g[1][u], g[2][u], g[3][u], g[4][u]);
    };
    // lossless power-of-two rescale; alphas >= 0 so hi-word int order == value order
    auto rescale = [&]() {
        int h = __double2hiint(a0);
        int h1 = __double2hiint(a1); h = (h1 > h) ? h1 : h;
        h1 = __double2hiint(a2);     h = (h1 > h) ? h1 : h;
        h1 = __double2hiint(a3);     h = (h1 > h) ? h1 : h;
        h1 = __double2hiint(a4);     h = (h1 > h) ? h1 : h;
        h1 = __double2hiint(a5);     h = (h1 > h) ? h1 : h;
        h1 = __double2hiint(a6);     h = (h1 > h) ? h1 : h;
        h1 = __double2hiint(a7);     h = (h1 > h) ? h1 : h;
        #pragma unroll
        for (int o = 1; o < 64; o <<= 1) {
            const int hx = __shfl_xor(h, o, 64);
            h = (hx > h) ? hx : h;
        }
        if (h > 0) {
            const int be_ = h >> 20;             // biased exponent (sign=0)
            const int ex  = be_ - 1022;          // max = f*2^ex, f in [0.5,1)
            const double sf = __hiloint2double((2045 - be_) << 20, 0);  // 2^-ex exact
            a0 *= sf; a1 *= sf; a2 *= sf; a3 *= sf;
            a4 *= sf; a5 *= sf; a6 *= sf; a7 *= sf;
            logscale += (double)ex * 0.6931471805599453;
        }
    };

    // 250 8-step blocks: block 0 = t 1..7, blocks 1..249 = 8 t's each.
    // Double-buffered g0/g1, rescale every 4 blocks (32 steps).
    for (int it = 0; it < 125; ++it) {
        const int t = 16 * it;
        prefetch(g1);                            // t+8 .. t+15
        if (t + 16 <= len) {                     // wave-uniform fast path
            run8f(g0, (it == 0) ? 1 : 0);
            if (it < 124) prefetch(g0);          // t+16 .. t+23
            run8f(g1, 0);
        } else {
            run8c(g0, t, (it == 0) ? 1 : 0);
            if (it < 124) prefetch(g0);
            run8c(g1, t + 8, 0);
        }
        if (it & 1) rescale();
    }

    // readout: alpha at states 2*tl and 2*tl-1
    double contrib = 0.0;
    const int send = 2 * tl;
    #pragma unroll
    for (int i = 0; i < 8; ++i) {
        const int s = 8 * l + i;
        const double av = (i == 0) ? a0 : (i == 1) ? a1 : (i == 2) ? a2 :
                          (i == 3) ? a3 : (i == 4) ? a4 : (i == 5) ? a5 :
                          (i == 6) ? a6 : a7;
        if (s == send || s == send - 1) contrib += av;
    }
    #pragma unroll
    for (int o = 32; o > 0; o >>= 1) contrib += __shfl_xor(contrib, o, 64);

    if (l == 0) {
        double lb = 0.0;
        if (contrib > 0.0) lb = -(log(contrib) + logscale);
        if (lb > 1e29) lb = 0.0;                 // zero_infinity
        loss_ws[b] = (float)(lb / (double)tl);
    }
}

// ---------------------------------------------------------------------------
// k3: mean over batches -> final loss scalar.
// ---------------------------------------------------------------------------
__global__ void k3_reduce(const float* __restrict__ ws, float* __restrict__ loss_out)
{
    if (threadIdx.x == 0 && blockIdx.x == 0) {
        float sum = 0.0f;
        #pragma unroll
        for (int b = 0; b < BB; ++b) sum += ws[b];
        *loss_out = sum / (float)BB;
    }
}

// ===========================================================================
// FALLBACK path (round-3, proven): used only if ws_size too small for P.
// ===========================================================================
__global__ __launch_bounds__(256) void k1_lds(
    const float* __restrict__ hidden, const float* __restrict__ W,
    const float* __restrict__ bias, float* __restrict__ out)
{
    __shared__ float Wl[CC * 256];
    float4* Wl4 = (float4*)Wl;
    const int tid = threadIdx.x;
    const int r = blockIdx.x * blockDim.x + tid;
    const float4* __restrict__ h4 = (const float4*)(hidden + (size_t)r * HH);
    const float4* __restrict__ W4g = (const float4*)W;
    float acc[CC];
    #pragma unroll
    for (int c = 0; c < CC; ++c) acc[c] = 0.0f;
    for (int kc = 0; kc < 2; ++kc) {
        __syncthreads();
        #pragma unroll
        for (int i = 0; i < 10; ++i) {
            const int idx = tid + i * 256;
            const int c = idx >> 6, j4 = idx & 63;
            Wl4[idx] = W4g[c * 128 + kc * 64 + j4];
        }
        __syncthreads();
        #pragma unroll 2
        for (int k4 = 0; k4 < 64; ++k4) {
            const float4 h = h4[kc * 64 + k4];
            #pragma unroll
            for (int c = 0; c < CC; ++c) {
                const float4 w = Wl4[c * 64 + k4];
                acc[c] = fmaf(h.x, w.x, fmaf(h.y, w.y,
                         fmaf(h.z, w.z, fmaf(h.w, w.w, acc[c]))));
            }
        }
    }
    #pragma unroll
    for (int c = 0; c < CC; ++c) acc[c] += bias[c];
    float mx = acc[0];
    #pragma unroll
    for (int c = 1; c < CC; ++c) mx = fmaxf(mx, acc[c]);
    float s = 0.0f;
    #pragma unroll
    for (int c = 0; c < CC; ++c) s += __expf(acc[c] - mx);
    const float lse = mx + __logf(s);
    const int b = r / TT, t = r - b * TT;
    float4* __restrict__ o4 = (float4*)(out + ((size_t)t * BB + b) * CC);
    #pragma unroll
    for (int c4 = 0; c4 < CC / 4; ++c4) {
        float4 v;
        v.x = acc[4 * c4 + 0] - lse; v.y = acc[4 * c4 + 1] - lse;
        v.z = acc[4 * c4 + 2] - lse; v.w = acc[4 * c4 + 3] - lse;
        o4[c4] = v;
    }
}

__device__ __forceinline__ float bperm(int byteaddr, float v) {
    return __int_as_float(__builtin_amdgcn_ds_bpermute(byteaddr, __float_as_int(v)));
}

__global__ __launch_bounds__(64) void k2_legacy(
    const float* __restrict__ lp, const int* __restrict__ targets,
    const int* __restrict__ input_lengths, const int* __restrict__ target_lengths,
    float* __restrict__ ws)
{
    const int b = blockIdx.x, lane = threadIdx.x;
    const int len = input_lengths[b];
    const int tl = target_lengths[b];
    const int S = 2 * tl + 1;
    int cad[7]; double skf[7];
    #pragma unroll
    for (int i = 0; i < 7; ++i) {
        const int s = 7 * lane + i;
        int cls = 63; double sk = 0.0;
        if (s < S) {
            if (s & 1) {
                cls = targets[b * LL + (s >> 1)];
                if (s >= 3) sk = (cls != targets[b * LL + ((s - 3) >> 1)]) ? 1.0 : 0.0;
                else sk = 1.0;
            } else cls = CC - 1;
        }
        cad[i] = cls * 4; skf[i] = sk;
    }
    const double lane0m = (lane == 0) ? 0.0 : 1.0;
    const int lc = (lane < CC) ? lane : (CC - 1);
    const size_t rowstride = (size_t)BB * CC;
    const float* lprow = lp + (size_t)b * CC + lc;
    double a0, a1, a2, a3, a4, a5, a6;
    {
        const float v0 = lprow[0];
        const float e = (lane < CC) ? __expf(v0) : 0.0f;
        a0 = (lane == 0) ? (double)bperm(cad[0], e) : 0.0;
        a1 = (lane == 0) ? (double)bperm(cad[1], e) : 0.0;
        a2 = a3 = a4 = a5 = a6 = 0.0;
    }
    float Pr[8];
    #pragma unroll
    for (int u = 0; u < 8; ++u) Pr[u] = lprow[(size_t)(1 + u) * rowstride];
    double logscale = 0.0;
    auto step = [&](int t, float pv) {
        const float ef = (lane < CC) ? __expf(pv) : 0.0f;
        const double e0 = (double)bperm(cad[0], ef), e1 = (double)bperm(cad[1], ef);
        const double e2 = (double)bperm(cad[2], ef), e3 = (double)bperm(cad[3], ef);
        const double e4 = (double)bperm(cad[4], ef), e5 = (double)bperm(cad[5], ef);
        const double e6 = (double)bperm(cad[6], ef);
        const double pl1 = __shfl_up(a6, 1, 64) * lane0m;
        const double pl2 = __shfl_up(a5, 1, 64) * lane0m;
        const double n0 = (a0 + fma(skf[0], pl2, pl1)) * e0;
        const double n1 = (a1 + fma(skf[1], pl1, a0)) * e1;
        const double n2 = (a2 + fma(skf[2], a0, a1)) * e2;
        const double n3 = (a3 + fma(skf[3], a1, a2)) * e3;
        const double n4 = (a4 + fma(skf[4], a2, a3)) * e4;
        const double n5 = (a5 + fma(skf[5], a3, a4)) * e5;
        const double n6 = (a6 + fma(skf[6], a4, a5)) * e6;
        if (t < len) { a0 = n0; a1 = n1; a2 = n2; a3 = n3; a4 = n4; a5 = n5; a6 = n6; }
    };
    auto rescale = [&]() {
        double m = fmax(fmax(fmax(a0, a1), fmax(a2, a3)), fmax(fmax(a4, a5), a6));
        #pragma unroll
        for (int o = 32; o > 0; o >>= 1) m = fmax(m, __shfl_xor(m, o, 64));
        if (m > 0.0) {
            const double inv = 1.0 / m;
            a0 *= inv; a1 *= inv; a2 *= inv; a3 *= inv; a4 *= inv; a5 *= inv; a6 *= inv;
            logscale += (double)__logf((float)m);
        }
    };
    for (int it = 0; it < 249; ++it) {
        const int t = 1 + it * 8, tb = t + 8;
        const float* pf = lprow + (size_t)tb * rowstride;
        float q[8];
        #pragma unroll
        for (int u = 0; u < 8; ++u) q[u] = (tb + u < TT) ? pf[(size_t)u * rowstride] : 0.0f;
        #pragma unroll
        for (int u = 0; u < 8; ++u) step(t + u, Pr[u]);
        rescale();
        #pragma unroll
        for (int u = 0; u < 8; ++u) Pr[u] = q[u];
    }
    #pragma unroll
    for (int u = 0; u < 7; ++u) step(1993 + u, Pr[u]);
    double contrib = 0.0;
    #pragma unroll
    for (int i = 0; i < 7; ++i) {
        const int s = 7 * lane + i;
        const double av = (i == 0) ? a0 : (i == 1) ? a1 : (i == 2) ? a2 :
                          (i == 3) ? a3 : (i == 4) ? a4 : (i == 5) ? a5 : a6;
        if (s == 2 * tl || s == 2 * tl - 1) contrib += av;
    }
    #pragma unroll
    for (int o = 32; o > 0; o >>= 1) contrib += __shfl_xor(contrib, o, 64);
    if (lane == 0) {
        double lb = 0.0;
        if (contrib > 0.0) lb = -(log(contrib) + logscale);
        if (lb > 1e29) lb = 0.0;
        ws[b] = (float)(lb / (double)tl);
    }
}

extern "C" void kernel_launch(void* const* d_in, const int* in_sizes, int n_in,
                              void* d_out, int out_size, void* d_ws, size_t ws_size,
                              hipStream_t stream) {
    const float* hidden = (const float*)d_in[0];
    const float* W      = (const float*)d_in[1];
    const float* bias   = (const float*)d_in[2];
    const int* targets  = (const int*)d_in[3];
    const int* in_len   = (const int*)d_in[4];
    const int* tg_len   = (const int*)d_in[5];

    float* out      = (float*)d_out;
    float* loss_out = out + (size_t)TT * BB * CC;

    const size_t PELEMS   = (size_t)BB * CC * TT;                 // 2,560,000 floats
    const size_t WBF_OFF  = PELEMS;                                // float offset
    const size_t LOSS_OFF = PELEMS + (48 * HH * sizeof(short)) / sizeof(float);
    const size_t need     = (LOSS_OFF + BB) * sizeof(float);       // ~10.3 MB

    if (ws_size >= need) {
        float* P   = (float*)d_ws;                                 // (B,T,C)
        short* wbf = (short*)((float*)d_ws + WBF_OFF);             // (48,H) bf16
        float* lws = (float*)d_ws + LOSS_OFF;                      // (B,)
        k0_wconv<<<dim3(96), dim3(256), 0, stream>>>(W, wbf);
        k1_mfma<<<dim3(1000), dim3(256), 0, stream>>>(hidden, wbf, bias, out, P);
        k2_fast<<<dim3(BB), dim3(64), 0, stream>>>(P, targets, in_len, tg_len, lws);
        k3_reduce<<<dim3(1), dim3(64), 0, stream>>>(lws, loss_out);
    } else {
        float* lws = (float*)d_ws;
        k1_lds<<<dim3((BB * TT) / 256), dim3(256), 0, stream>>>(hidden, W, bias, out);
        k2_legacy<<<dim3(BB), dim3(64), 0, stream>>>(out, targets, in_len, tg_len, lws);
        k3_reduce<<<dim3(1), dim3(64), 0, stream>>>(lws, loss_out);
    }
}

// Round 5
// 384.104 us; speedup vs baseline: 1.0721x; 1.0721x over previous
//
#include <hip/hip_runtime.h>
#include <hip/hip_bf16.h>

// Problem constants (from reference setup_inputs):
//   B=32, T=2000, H=512, L=200, C=40 (39 phones + blank=39)
// Outputs: log_prob (T,B,C) fp32 flat [0, 2560000) then loss scalar at [2560000].

#define BB 32
#define TT 2000
#define HH 512
#define CC 40
#define LL 200
#define NEGV -1e30f

typedef __attribute__((ext_vector_type(8))) short short8;
typedef __attribute__((ext_vector_type(4))) float f32x4;

__device__ __forceinline__ unsigned short f2bf(float f) {
    unsigned u = __float_as_uint(f);
    u = u + 0x7FFFu + ((u >> 16) & 1u);      // RNE truncate to bf16
    return (unsigned short)(u >> 16);
}

// lane i gets lane i-1's value; lane 0 gets 0. VALU DPP (wave_shr:1), no DS.
// PROVEN on gfx950 (round-0 baseline, 395us).
__device__ __forceinline__ double dshr1(double x) {
    int lo = __double2loint(x), hi = __double2hiint(x);
    lo = __builtin_amdgcn_update_dpp(0, lo, 0x138, 0xF, 0xF, false);
    hi = __builtin_amdgcn_update_dpp(0, hi, 0x138, 0xF, 0xF, false);
    return __hiloint2double(hi, lo);
}

// ---------------------------------------------------------------------------
// k0: convert W (C,H) fp32 -> padded bf16 (48,H), classes >= 40 zero.
// ---------------------------------------------------------------------------
__global__ void k0_wconv(const float* __restrict__ W, short* __restrict__ wbf) {
    const int idx = blockIdx.x * 256 + threadIdx.x;
    if (idx < 48 * HH) {
        const int n = idx >> 9, k = idx & (HH - 1);
        wbf[idx] = (n < CC) ? (short)f2bf(W[n * HH + k]) : (short)0;
    }
}

// ---------------------------------------------------------------------------
// k1 (fast): MFMA GEMM + log-softmax. One wave per 16 rows; N=48 (3 tiles),
// K=512 in 16 steps of 32. A: fp32 global -> bf16 in-register. B: bf16 from
// k0's buffer (cache-resident, 48 KB). No LDS, no barriers.
// C/D layout: col=lane&15, row=quad*4+reg. A: row=lane&15, k=quad*8+j.
// Writes P = exp(log_prob) as (B,T,C) rows so k2 can stage whole t-chunks
// with coalesced float4 loads.
// ---------------------------------------------------------------------------
__global__ __launch_bounds__(256) void k1_mfma(
    const float* __restrict__ hidden,   // (B,T,H)
    const short* __restrict__ wbf,      // (48,H) bf16
    const float* __restrict__ bias,     // (C,)
    float* __restrict__ out,            // (T,B,C)
    float* __restrict__ P)              // (B,T,C) probs
{
    const int tid = threadIdx.x, lane = tid & 63, wv = tid >> 6;
    const int quad = lane >> 4, mcol = lane & 15;
    const int r0 = (blockIdx.x * 4 + wv) * 16;

    const float* aptr = hidden + (size_t)(r0 + mcol) * HH + quad * 8;
    const short* b0p = wbf + (0 * 16 + mcol) * HH + quad * 8;
    const short* b1p = wbf + (1 * 16 + mcol) * HH + quad * 8;
    const short* b2p = wbf + (2 * 16 + mcol) * HH + quad * 8;

    f32x4 acc0 = {0.f, 0.f, 0.f, 0.f};
    f32x4 acc1 = {0.f, 0.f, 0.f, 0.f};
    f32x4 acc2 = {0.f, 0.f, 0.f, 0.f};

    #pragma unroll 2
    for (int kc = 0; kc < 16; ++kc) {
        const float4 al = *(const float4*)(aptr + kc * 32);
        const float4 ah = *(const float4*)(aptr + kc * 32 + 4);
        short8 af;
        af[0] = f2bf(al.x); af[1] = f2bf(al.y); af[2] = f2bf(al.z); af[3] = f2bf(al.w);
        af[4] = f2bf(ah.x); af[5] = f2bf(ah.y); af[6] = f2bf(ah.z); af[7] = f2bf(ah.w);
        const short8 bf0 = *(const short8*)(b0p + kc * 32);
        const short8 bf1 = *(const short8*)(b1p + kc * 32);
        const short8 bf2 = *(const short8*)(b2p + kc * 32);
        acc0 = __builtin_amdgcn_mfma_f32_16x16x32_bf16(af, bf0, acc0, 0, 0, 0);
        acc1 = __builtin_amdgcn_mfma_f32_16x16x32_bf16(af, bf1, acc1, 0, 0, 0);
        acc2 = __builtin_amdgcn_mfma_f32_16x16x32_bf16(af, bf2, acc2, 0, 0, 0);
    }

    // epilogue: bias, row-wise log-softmax over 40 cols (cols 40-47 masked)
    const float bz0 = bias[mcol];
    const float bz1 = bias[16 + mcol];
    const float bz2 = (mcol < 8) ? bias[32 + mcol] : 0.0f;
    float L0[4], L1[4], L2[4], lse[4];
    #pragma unroll
    for (int j = 0; j < 4; ++j) {
        L0[j] = acc0[j] + bz0;
        L1[j] = acc1[j] + bz1;
        L2[j] = (mcol < 8) ? (acc2[j] + bz2) : NEGV;
    }
    #pragma unroll
    for (int j = 0; j < 4; ++j) {
        float m = fmaxf(fmaxf(L0[j], L1[j]), L2[j]);
        #pragma unroll
        for (int o = 1; o < 16; o <<= 1) m = fmaxf(m, __shfl_xor(m, o, 64));
        float s = __expf(L0[j] - m) + __expf(L1[j] - m)
                + ((mcol < 8) ? __expf(L2[j] - m) : 0.0f);
        #pragma unroll
        for (int o = 1; o < 16; o <<= 1) s += __shfl_xor(s, o, 64);
        lse[j] = m + __logf(s);
    }
    #pragma unroll
    for (int j = 0; j < 4; ++j) {
        const int r = r0 + quad * 4 + j;
        const int b = r / TT, t = r - b * TT;
        float* op = out + ((size_t)t * BB + b) * CC;
        float* pp = P + (size_t)r * CC;          // (B,T,C): r = b*TT + t
        const float v0 = L0[j] - lse[j];
        const float v1 = L1[j] - lse[j];
        op[mcol]      = v0;  pp[mcol]      = __expf(v0);
        op[16 + mcol] = v1;  pp[16 + mcol] = __expf(v1);
        if (mcol < 8) {
            const float v2 = L2[j] - lse[j];
            op[32 + mcol] = v2;  pp[32 + mcol] = __expf(v2);
        }
    }
}

// ---------------------------------------------------------------------------
// k2 (fast): CTC alpha recurrence, one wave per batch, 8 states/lane
// (s = 8*lane + i; even i = blank). FP64 linear domain (proven numerics).
// ROUND-5 CHANGE: LDS chunk staging. P is (B,T,C); a 40-step chunk (6400 B)
// is staged into LDS with 7 COALESCED loads (float4/lane), double-buffered.
// Loads for chunk c+1 are issued a FULL chunk (~5000 cyc of compute) before
// their ds_write consumes them -> HBM latency structurally hidden; the one
// vmcnt drain per chunk sits right before the ds_writes. Per-step emissions
// come from LDS: 4 per-lane ds_read_b32 gathers (bank=(8u+c)%32, conflict-
// free except rare c vs c+32 aliases) + 1 uniform-broadcast blank read.
// This replaces per-8-step scattered global gathers that exposed ~900+ cyc
// of cross-XCD L3/HBM latency per block (rounds 0-4: ~226 cyc/step).
// Rescale every 40 steps, lossless pow2 (worst drift -12*40=-480 >> -708).
// ---------------------------------------------------------------------------
__global__ __launch_bounds__(64) void k2_fast(
    const float* __restrict__ P,             // (B,T,C) probs
    const int* __restrict__ targets,         // (B,L)
    const int* __restrict__ input_lengths,   // (B,)
    const int* __restrict__ target_lengths,  // (B,)
    float* __restrict__ loss_ws)             // (B,)
{
    const int b = blockIdx.x, l = threadIdx.x;
    const int len = input_lengths[b];
    const int tl  = target_lengths[b];

    __shared__ float ldsP[2][40 * CC];       // 2 x 6400 B

    // odd states of this lane: s = 8l + 2j+1 -> label index 4l + j
    int cls[4]; double sk[4];
    #pragma unroll
    for (int j = 0; j < 4; ++j) {
        const int idx = 4 * l + j;
        int c = CC - 1; double skv = 0.0;
        if (idx < tl) {
            c = targets[b * LL + idx];
            if (idx == 0) skv = 1.0;   // s==1: a[s-2] is 0; skip=true in ref
            else skv = (c != targets[b * LL + idx - 1]) ? 1.0 : 0.0;
        }
        cls[j] = c; sk[j] = skv;
    }
    const int off0 = cls[0], off1 = cls[1], off2 = cls[2], off3 = cls[3];

    const float* Pb = P + (size_t)b * TT * CC;
    const int lane4 = l * 4;

    // register staging: 1600 floats/chunk = 6 x (64 lanes x float4) + 64 x f32
    float4 st[6]; float st6;
    auto stage_load = [&](int chunk) {       // issue coalesced loads (no wait)
        const float* src = Pb + (size_t)chunk * (40 * CC);
        #pragma unroll
        for (int i = 0; i < 6; ++i)
            st[i] = *(const float4*)(src + i * 256 + lane4);
        st6 = src[1536 + l];
    };
    auto stage_write = [&](int par) {        // vmcnt wait lands here
        float* dst = ldsP[par];
        #pragma unroll
        for (int i = 0; i < 6; ++i)
            *(float4*)(dst + i * 256 + lane4) = st[i];
        dst[1536 + l] = st6;
    };

    stage_load(0);
    stage_write(0);

    // t = 0 init (from LDS row 0)
    double a0, a1, a2, a3, a4, a5, a6, a7;
    {
        const float pb0 = ldsP[0][CC - 1];
        const float pl0 = ldsP[0][off0];
        a0 = (l == 0) ? (double)pb0 : 0.0;
        a1 = (l == 0) ? (double)pl0 : 0.0;
        a2 = a3 = a4 = a5 = a6 = a7 = 0.0;
    }

    stage_load(1);                           // in flight across chunk 0

    double logscale = 0.0;

    auto step = [&](float e1f, float e3f, float e5f, float e7f, float bef) {
        const double be = (double)bef;
        const double p7 = dshr1(a7);         // prev lane's state 8l-1
        const double n0 = (a0 + p7) * be;
        const double n1 = (a1 + fma(sk[0], p7, a0)) * (double)e1f;
        const double n2 = (a2 + a1) * be;
        const double n3 = (a3 + fma(sk[1], a1, a2)) * (double)e3f;
        const double n4 = (a4 + a3) * be;
        const double n5 = (a5 + fma(sk[2], a3, a4)) * (double)e5f;
        const double n6 = (a6 + a5) * be;
        const double n7 = (a7 + fma(sk[3], a5, a6)) * (double)e7f;
        a0 = n0; a1 = n1; a2 = n2; a3 = n3;
        a4 = n4; a5 = n5; a6 = n6; a7 = n7;
    };
    auto dostep = [&](const float* row) {
        step(row[off0], row[off1], row[off2], row[off3], row[CC - 1]);
    };
    // lossless power-of-two rescale; alphas >= 0 so hi-word int order == value order
    auto rescale = [&]() {
        int h = __double2hiint(a0);
        int h1 = __double2hiint(a1); h = (h1 > h) ? h1 : h;
        h1 = __double2hiint(a2);     h = (h1 > h) ? h1 : h;
        h1 = __double2hiint(a3);     h = (h1 > h) ? h1 : h;
        h1 = __double2hiint(a4);     h = (h1 > h) ? h1 : h;
        h1 = __double2hiint(a5);     h = (h1 > h) ? h1 : h;
        h1 = __double2hiint(a6);     h = (h1 > h) ? h1 : h;
        h1 = __double2hiint(a7);     h = (h1 > h) ? h1 : h;
        #pragma unroll
        for (int o = 1; o < 64; o <<= 1) {
            const int hx = __shfl_xor(h, o, 64);
            h = (hx > h) ? hx : h;
        }
        if (h > 0) {
            const int be_ = h >> 20;             // biased exponent (sign=0)
            const int ex  = be_ - 1022;          // max = f*2^ex, f in [0.5,1)
            const double sf = __hiloint2double((2045 - be_) << 20, 0);  // 2^-ex exact
            a0 *= sf; a1 *= sf; a2 *= sf; a3 *= sf;
            a4 *= sf; a5 *= sf; a6 *= sf; a7 *= sf;
            logscale += (double)ex * 0.6931471805599453;
        }
    };

    // 50 chunks x 40 steps. Chunk 0 runs u=1..39 (t=0 consumed by init).
    for (int c = 0; c < 50; ++c) {
        const int par = c & 1;
        const float* buf = ldsP[par];
        const int tbase = c * 40;
        if (tbase + 40 <= len) {             // wave-uniform fast path
            if (c == 0) {
                #pragma unroll 8
                for (int u = 1; u < 40; ++u) dostep(buf + u * CC);
            } else {
                #pragma unroll 8
                for (int u = 0; u < 40; ++u) dostep(buf + u * CC);
            }
        } else {                             // checked tail (len < T only)
            const int u0 = (c == 0) ? 1 : 0;
            for (int u = u0; u < 40; ++u)
                if (tbase + u < len) dostep(buf + u * CC);
        }
        rescale();
        if (c < 49) {
            stage_write(par ^ 1);            // waits on chunk c+1's loads
            if (c < 48) stage_load(c + 2);   // issue next chunk's loads
        }
    }

    // readout: alpha at states 2*tl and 2*tl-1
    double contrib = 0.0;
    const int send = 2 * tl;
    #pragma unroll
    for (int i = 0; i < 8; ++i) {
        const int s = 8 * l + i;
        const double av = (i == 0) ? a0 : (i == 1) ? a1 : (i == 2) ? a2 :
                          (i == 3) ? a3 : (i == 4) ? a4 : (i == 5) ? a5 :
                          (i == 6) ? a6 : a7;
        if (s == send || s == send - 1) contrib += av;
    }
    #pragma unroll
    for (int o = 32; o > 0; o >>= 1) contrib += __shfl_xor(contrib, o, 64);

    if (l == 0) {
        double lb = 0.0;
        if (contrib > 0.0) lb = -(log(contrib) + logscale);
        if (lb > 1e29) lb = 0.0;                 // zero_infinity
        loss_ws[b] = (float)(lb / (double)tl);
    }
}

// ---------------------------------------------------------------------------
// k3: mean over batches -> final loss scalar.
// ---------------------------------------------------------------------------
__global__ void k3_reduce(const float* __restrict__ ws, float* __restrict__ loss_out)
{
    if (threadIdx.x == 0 && blockIdx.x == 0) {
        float sum = 0.0f;
        #pragma unroll
        for (int b = 0; b < BB; ++b) sum += ws[b];
        *loss_out = sum / (float)BB;
    }
}

// ===========================================================================
// FALLBACK path (round-3, proven): used only if ws_size too small for P.
// ===========================================================================
__global__ __launch_bounds__(256) void k1_lds(
    const float* __restrict__ hidden, const float* __restrict__ W,
    const float* __restrict__ bias, float* __restrict__ out)
{
    __shared__ float Wl[CC * 256];
    float4* Wl4 = (float4*)Wl;
    const int tid = threadIdx.x;
    const int r = blockIdx.x * blockDim.x + tid;
    const float4* __restrict__ h4 = (const float4*)(hidden + (size_t)r * HH);
    const float4* __restrict__ W4g = (const float4*)W;
    float acc[CC];
    #pragma unroll
    for (int c = 0; c < CC; ++c) acc[c] = 0.0f;
    for (int kc = 0; kc < 2; ++kc) {
        __syncthreads();
        #pragma unroll
        for (int i = 0; i < 10; ++i) {
            const int idx = tid + i * 256;
            const int c = idx >> 6, j4 = idx & 63;
            Wl4[idx] = W4g[c * 128 + kc * 64 + j4];
        }
        __syncthreads();
        #pragma unroll 2
        for (int k4 = 0; k4 < 64; ++k4) {
            const float4 h = h4[kc * 64 + k4];
            #pragma unroll
            for (int c = 0; c < CC; ++c) {
                const float4 w = Wl4[c * 64 + k4];
                acc[c] = fmaf(h.x, w.x, fmaf(h.y, w.y,
                         fmaf(h.z, w.z, fmaf(h.w, w.w, acc[c]))));
            }
        }
    }
    #pragma unroll
    for (int c = 0; c < CC; ++c) acc[c] += bias[c];
    float mx = acc[0];
    #pragma unroll
    for (int c = 1; c < CC; ++c) mx = fmaxf(mx, acc[c]);
    float s = 0.0f;
    #pragma unroll
    for (int c = 0; c < CC; ++c) s += __expf(acc[c] - mx);
    const float lse = mx + __logf(s);
    const int b = r / TT, t = r - b * TT;
    float4* __restrict__ o4 = (float4*)(out + ((size_t)t * BB + b) * CC);
    #pragma unroll
    for (int c4 = 0; c4 < CC / 4; ++c4) {
        float4 v;
        v.x = acc[4 * c4 + 0] - lse; v.y = acc[4 * c4 + 1] - lse;
        v.z = acc[4 * c4 + 2] - lse; v.w = acc[4 * c4 + 3] - lse;
        o4[c4] = v;
    }
}

__device__ __forceinline__ float bperm(int byteaddr, float v) {
    return __int_as_float(__builtin_amdgcn_ds_bpermute(byteaddr, __float_as_int(v)));
}

__global__ __launch_bounds__(64) void k2_legacy(
    const float* __restrict__ lp, const int* __restrict__ targets,
    const int* __restrict__ input_lengths, const int* __restrict__ target_lengths,
    float* __restrict__ ws)
{
    const int b = blockIdx.x, lane = threadIdx.x;
    const int len = input_lengths[b];
    const int tl = target_lengths[b];
    const int S = 2 * tl + 1;
    int cad[7]; double skf[7];
    #pragma unroll
    for (int i = 0; i < 7; ++i) {
        const int s = 7 * lane + i;
        int cls = 63; double sk = 0.0;
        if (s < S) {
            if (s & 1) {
                cls = targets[b * LL + (s >> 1)];
                if (s >= 3) sk = (cls != targets[b * LL + ((s - 3) >> 1)]) ? 1.0 : 0.0;
                else sk = 1.0;
            } else cls = CC - 1;
        }
        cad[i] = cls * 4; skf[i] = sk;
    }
    const double lane0m = (lane == 0) ? 0.0 : 1.0;
    const int lc = (lane < CC) ? lane : (CC - 1);
    const size_t rowstride = (size_t)BB * CC;
    const float* lprow = lp + (size_t)b * CC + lc;
    double a0, a1, a2, a3, a4, a5, a6;
    {
        const float v0 = lprow[0];
        const float e = (lane < CC) ? __expf(v0) : 0.0f;
        a0 = (lane == 0) ? (double)bperm(cad[0], e) : 0.0;
        a1 = (lane == 0) ? (double)bperm(cad[1], e) : 0.0;
        a2 = a3 = a4 = a5 = a6 = 0.0;
    }
    float Pr[8];
    #pragma unroll
    for (int u = 0; u < 8; ++u) Pr[u] = lprow[(size_t)(1 + u) * rowstride];
    double logscale = 0.0;
    auto step = [&](int t, float pv) {
        const float ef = (lane < CC) ? __expf(pv) : 0.0f;
        const double e0 = (double)bperm(cad[0], ef), e1 = (double)bperm(cad[1], ef);
        const double e2 = (double)bperm(cad[2], ef), e3 = (double)bperm(cad[3], ef);
        const double e4 = (double)bperm(cad[4], ef), e5 = (double)bperm(cad[5], ef);
        const double e6 = (double)bperm(cad[6], ef);
        const double pl1 = __shfl_up(a6, 1, 64) * lane0m;
        const double pl2 = __shfl_up(a5, 1, 64) * lane0m;
        const double n0 = (a0 + fma(skf[0], pl2, pl1)) * e0;
        const double n1 = (a1 + fma(skf[1], pl1, a0)) * e1;
        const double n2 = (a2 + fma(skf[2], a0, a1)) * e2;
        const double n3 = (a3 + fma(skf[3], a1, a2)) * e3;
        const double n4 = (a4 + fma(skf[4], a2, a3)) * e4;
        const double n5 = (a5 + fma(skf[5], a3, a4)) * e5;
        const double n6 = (a6 + fma(skf[6], a4, a5)) * e6;
        if (t < len) { a0 = n0; a1 = n1; a2 = n2; a3 = n3; a4 = n4; a5 = n5; a6 = n6; }
    };
    auto rescale = [&]() {
        double m = fmax(fmax(fmax(a0, a1), fmax(a2, a3)), fmax(fmax(a4, a5), a6));
        #pragma unroll
        for (int o = 32; o > 0; o >>= 1) m = fmax(m, __shfl_xor(m, o, 64));
        if (m > 0.0) {
            const double inv = 1.0 / m;
            a0 *= inv; a1 *= inv; a2 *= inv; a3 *= inv; a4 *= inv; a5 *= inv; a6 *= inv;
            logscale += (double)__logf((float)m);
        }
    };
    for (int it = 0; it < 249; ++it) {
        const int t = 1 + it * 8, tb = t + 8;
        const float* pf = lprow + (size_t)tb * rowstride;
        float q[8];
        #pragma unroll
        for (int u = 0; u < 8; ++u) q[u] = (tb + u < TT) ? pf[(size_t)u * rowstride] : 0.0f;
        #pragma unroll
        for (int u = 0; u < 8; ++u) step(t + u, Pr[u]);
        rescale();
        #pragma unroll
        for (int u = 0; u < 8; ++u) Pr[u] = q[u];
    }
    #pragma unroll
    for (int u = 0; u < 7; ++u) step(1993 + u, Pr[u]);
    double contrib = 0.0;
    #pragma unroll
    for (int i = 0; i < 7; ++i) {
        const int s = 7 * lane + i;
        const double av = (i == 0) ? a0 : (i == 1) ? a1 : (i == 2) ? a2 :
                          (i == 3) ? a3 : (i == 4) ? a4 : (i == 5) ? a5 : a6;
        if (s == 2 * tl || s == 2 * tl - 1) contrib += av;
    }
    #pragma unroll
    for (int o = 32; o > 0; o >>= 1) contrib += __shfl_xor(contrib, o, 64);
    if (lane == 0) {
        double lb = 0.0;
        if (contrib > 0.0) lb = -(log(contrib) + logscale);
        if (lb > 1e29) lb = 0.0;
        ws[b] = (float)(lb / (double)tl);
    }
}

extern "C" void kernel_launch(void* const* d_in, const int* in_sizes, int n_in,
                              void* d_out, int out_size, void* d_ws, size_t ws_size,
                              hipStream_t stream) {
    const float* hidden = (const float*)d_in[0];
    const float* W      = (const float*)d_in[1];
    const float* bias   = (const float*)d_in[2];
    const int* targets  = (const int*)d_in[3];
    const int* in_len   = (const int*)d_in[4];
    const int* tg_len   = (const int*)d_in[5];

    float* out      = (float*)d_out;
    float* loss_out = out + (size_t)TT * BB * CC;

    const size_t PELEMS   = (size_t)BB * CC * TT;                 // 2,560,000 floats
    const size_t WBF_OFF  = PELEMS;                                // float offset
    const size_t LOSS_OFF = PELEMS + (48 * HH * sizeof(short)) / sizeof(float);
    const size_t need     = (LOSS_OFF + BB) * sizeof(float);       // ~10.3 MB

    if (ws_size >= need) {
        float* P   = (float*)d_ws;                                 // (B,T,C)
        short* wbf = (short*)((float*)d_ws + WBF_OFF);             // (48,H) bf16
        float* lws = (float*)d_ws + LOSS_OFF;                      // (B,)
        k0_wconv<<<dim3(96), dim3(256), 0, stream>>>(W, wbf);
        k1_mfma<<<dim3(1000), dim3(256), 0, stream>>>(hidden, wbf, bias, out, P);
        k2_fast<<<dim3(BB), dim3(64), 0, stream>>>(P, targets, in_len, tg_len, lws);
        k3_reduce<<<dim3(1), dim3(64), 0, stream>>>(lws, loss_out);
    } else {
        float* lws = (float*)d_ws;
        k1_lds<<<dim3((BB * TT) / 256), dim3(256), 0, stream>>>(hidden, W, bias, out);
        k2_legacy<<<dim3(BB), dim3(64), 0, stream>>>(out, targets, in_len, tg_len, lws);
        k3_reduce<<<dim3(1), dim3(64), 0, stream>>>(lws, loss_out);
    }
}

// Round 6
// 371.994 us; speedup vs baseline: 1.1070x; 1.0326x over previous
//
#include <hip/hip_runtime.h>
#include <hip/hip_bf16.h>

// Problem constants (from reference setup_inputs):
//   B=32, T=2000, H=512, L=200, C=40 (39 phones + blank=39)
// Outputs: log_prob (T,B,C) fp32 flat [0, 2560000) then loss scalar at [2560000].

#define BB 32
#define TT 2000
#define HH 512
#define CC 40
#define LL 200
#define NEGV -1e30f

typedef __attribute__((ext_vector_type(8))) short short8;
typedef __attribute__((ext_vector_type(4))) float f32x4;

__device__ __forceinline__ unsigned short f2bf(float f) {
    unsigned u = __float_as_uint(f);
    u = u + 0x7FFFu + ((u >> 16) & 1u);      // RNE truncate to bf16
    return (unsigned short)(u >> 16);
}

// lane i gets lane i-1's value; lane 0 gets 0. VALU DPP (wave_shr:1), no DS.
// PROVEN on gfx950 (round-0 baseline, 395us).
__device__ __forceinline__ double dshr1(double x) {
    int lo = __double2loint(x), hi = __double2hiint(x);
    lo = __builtin_amdgcn_update_dpp(0, lo, 0x138, 0xF, 0xF, false);
    hi = __builtin_amdgcn_update_dpp(0, hi, 0x138, 0xF, 0xF, false);
    return __hiloint2double(hi, lo);
}

// ---------------------------------------------------------------------------
// k0: convert W (C,H) fp32 -> padded bf16 (48,H), classes >= 40 zero.
// ---------------------------------------------------------------------------
__global__ void k0_wconv(const float* __restrict__ W, short* __restrict__ wbf) {
    const int idx = blockIdx.x * 256 + threadIdx.x;
    if (idx < 48 * HH) {
        const int n = idx >> 9, k = idx & (HH - 1);
        wbf[idx] = (n < CC) ? (short)f2bf(W[n * HH + k]) : (short)0;
    }
}

// ---------------------------------------------------------------------------
// k1 (fast): MFMA GEMM + log-softmax. One wave per 16 rows; N=48 (3 tiles),
// K=512 in 16 steps of 32. A: fp32 global -> bf16 in-register. B: bf16 from
// k0's buffer (cache-resident, 48 KB). No LDS, no barriers.
// C/D layout: col=lane&15, row=quad*4+reg. A: row=lane&15, k=quad*8+j.
// Writes P = exp(log_prob) as (B,T,C) rows so k2 can stage whole t-chunks
// with coalesced float4 loads.
// ---------------------------------------------------------------------------
__global__ __launch_bounds__(256) void k1_mfma(
    const float* __restrict__ hidden,   // (B,T,H)
    const short* __restrict__ wbf,      // (48,H) bf16
    const float* __restrict__ bias,     // (C,)
    float* __restrict__ out,            // (T,B,C)
    float* __restrict__ P)              // (B,T,C) probs
{
    const int tid = threadIdx.x, lane = tid & 63, wv = tid >> 6;
    const int quad = lane >> 4, mcol = lane & 15;
    const int r0 = (blockIdx.x * 4 + wv) * 16;

    const float* aptr = hidden + (size_t)(r0 + mcol) * HH + quad * 8;
    const short* b0p = wbf + (0 * 16 + mcol) * HH + quad * 8;
    const short* b1p = wbf + (1 * 16 + mcol) * HH + quad * 8;
    const short* b2p = wbf + (2 * 16 + mcol) * HH + quad * 8;

    f32x4 acc0 = {0.f, 0.f, 0.f, 0.f};
    f32x4 acc1 = {0.f, 0.f, 0.f, 0.f};
    f32x4 acc2 = {0.f, 0.f, 0.f, 0.f};

    #pragma unroll 2
    for (int kc = 0; kc < 16; ++kc) {
        const float4 al = *(const float4*)(aptr + kc * 32);
        const float4 ah = *(const float4*)(aptr + kc * 32 + 4);
        short8 af;
        af[0] = f2bf(al.x); af[1] = f2bf(al.y); af[2] = f2bf(al.z); af[3] = f2bf(al.w);
        af[4] = f2bf(ah.x); af[5] = f2bf(ah.y); af[6] = f2bf(ah.z); af[7] = f2bf(ah.w);
        const short8 bf0 = *(const short8*)(b0p + kc * 32);
        const short8 bf1 = *(const short8*)(b1p + kc * 32);
        const short8 bf2 = *(const short8*)(b2p + kc * 32);
        acc0 = __builtin_amdgcn_mfma_f32_16x16x32_bf16(af, bf0, acc0, 0, 0, 0);
        acc1 = __builtin_amdgcn_mfma_f32_16x16x32_bf16(af, bf1, acc1, 0, 0, 0);
        acc2 = __builtin_amdgcn_mfma_f32_16x16x32_bf16(af, bf2, acc2, 0, 0, 0);
    }

    // epilogue: bias, row-wise log-softmax over 40 cols (cols 40-47 masked)
    const float bz0 = bias[mcol];
    const float bz1 = bias[16 + mcol];
    const float bz2 = (mcol < 8) ? bias[32 + mcol] : 0.0f;
    float L0[4], L1[4], L2[4], lse[4];
    #pragma unroll
    for (int j = 0; j < 4; ++j) {
        L0[j] = acc0[j] + bz0;
        L1[j] = acc1[j] + bz1;
        L2[j] = (mcol < 8) ? (acc2[j] + bz2) : NEGV;
    }
    #pragma unroll
    for (int j = 0; j < 4; ++j) {
        float m = fmaxf(fmaxf(L0[j], L1[j]), L2[j]);
        #pragma unroll
        for (int o = 1; o < 16; o <<= 1) m = fmaxf(m, __shfl_xor(m, o, 64));
        float s = __expf(L0[j] - m) + __expf(L1[j] - m)
                + ((mcol < 8) ? __expf(L2[j] - m) : 0.0f);
        #pragma unroll
        for (int o = 1; o < 16; o <<= 1) s += __shfl_xor(s, o, 64);
        lse[j] = m + __logf(s);
    }
    #pragma unroll
    for (int j = 0; j < 4; ++j) {
        const int r = r0 + quad * 4 + j;
        const int b = r / TT, t = r - b * TT;
        float* op = out + ((size_t)t * BB + b) * CC;
        float* pp = P + (size_t)r * CC;          // (B,T,C): r = b*TT + t
        const float v0 = L0[j] - lse[j];
        const float v1 = L1[j] - lse[j];
        op[mcol]      = v0;  pp[mcol]      = __expf(v0);
        op[16 + mcol] = v1;  pp[16 + mcol] = __expf(v1);
        if (mcol < 8) {
            const float v2 = L2[j] - lse[j];
            op[32 + mcol] = v2;  pp[32 + mcol] = __expf(v2);
        }
    }
}

// ---------------------------------------------------------------------------
// k2 (fast): CTC alpha recurrence, one wave per batch, 8 states/lane
// (s = 8*lane + i; even i = blank). FP64 linear domain (proven numerics).
// Two-level pipeline:
//   L1: global->LDS 40-step chunks, coalesced float4, double-buffered,
//       loads issued a full chunk (~4000+ cyc) before the vmcnt drain.
//   L2 (ROUND-6 CHANGE): LDS->register gather prefetch, 4 steps deep.
//       Rotating rows e0..e3; step u computes from e[u&3] and refills it
//       with row u+4 -> ~300 cyc of cover vs ~120 cyc ds_read latency,
//       which round 5 exposed per step (the ~95 cyc/step stall:
//       VALUBusy said only ~56% of the active SIMD was busy).
//       q-loop fully unrolled so row offsets fold into ds_read immediates.
// Rescale every 40 steps, lossless pow2 (worst drift -12*40=-480 >> -708).
// Generic checked path (len < T) kept non-pipelined for correctness.
// ---------------------------------------------------------------------------
__global__ __launch_bounds__(64) void k2_fast(
    const float* __restrict__ P,             // (B,T,C) probs
    const int* __restrict__ targets,         // (B,L)
    const int* __restrict__ input_lengths,   // (B,)
    const int* __restrict__ target_lengths,  // (B,)
    float* __restrict__ loss_ws)             // (B,)
{
    const int b = blockIdx.x, l = threadIdx.x;
    const int len = input_lengths[b];
    const int tl  = target_lengths[b];

    __shared__ float ldsP[2][40 * CC];       // 2 x 6400 B

    // odd states of this lane: s = 8l + 2j+1 -> label index 4l + j
    int cls[4]; double sk[4];
    #pragma unroll
    for (int j = 0; j < 4; ++j) {
        const int idx = 4 * l + j;
        int c = CC - 1; double skv = 0.0;
        if (idx < tl) {
            c = targets[b * LL + idx];
            if (idx == 0) skv = 1.0;   // s==1: a[s-2] is 0; skip=true in ref
            else skv = (c != targets[b * LL + idx - 1]) ? 1.0 : 0.0;
        }
        cls[j] = c; sk[j] = skv;
    }
    const int off0 = cls[0], off1 = cls[1], off2 = cls[2], off3 = cls[3];

    const float* Pb = P + (size_t)b * TT * CC;
    const int lane4 = l * 4;

    // register staging: 1600 floats/chunk = 6 x (64 lanes x float4) + 64 x f32
    float4 st[6]; float st6;
    auto stage_load = [&](int chunk) {       // issue coalesced loads (no wait)
        const float* src = Pb + (size_t)chunk * (40 * CC);
        #pragma unroll
        for (int i = 0; i < 6; ++i)
            st[i] = *(const float4*)(src + i * 256 + lane4);
        st6 = src[1536 + l];
    };
    auto stage_write = [&](int par) {        // vmcnt wait lands here
        float* dst = ldsP[par];
        #pragma unroll
        for (int i = 0; i < 6; ++i)
            *(float4*)(dst + i * 256 + lane4) = st[i];
        dst[1536 + l] = st6;
    };

    stage_load(0);
    stage_write(0);

    // t = 0 init (from LDS row 0)
    double a0, a1, a2, a3, a4, a5, a6, a7;
    {
        const float pb0 = ldsP[0][CC - 1];
        const float pl0 = ldsP[0][off0];
        a0 = (l == 0) ? (double)pb0 : 0.0;
        a1 = (l == 0) ? (double)pl0 : 0.0;
        a2 = a3 = a4 = a5 = a6 = a7 = 0.0;
    }

    stage_load(1);                           // in flight across chunk 0

    double logscale = 0.0;

    auto step = [&](float e1f, float e3f, float e5f, float e7f, float bef) {
        const double be = (double)bef;
        const double p7 = dshr1(a7);         // prev lane's state 8l-1
        const double n0 = (a0 + p7) * be;
        const double n1 = (a1 + fma(sk[0], p7, a0)) * (double)e1f;
        const double n2 = (a2 + a1) * be;
        const double n3 = (a3 + fma(sk[1], a1, a2)) * (double)e3f;
        const double n4 = (a4 + a3) * be;
        const double n5 = (a5 + fma(sk[2], a3, a4)) * (double)e5f;
        const double n6 = (a6 + a5) * be;
        const double n7 = (a7 + fma(sk[3], a5, a6)) * (double)e7f;
        a0 = n0; a1 = n1; a2 = n2; a3 = n3;
        a4 = n4; a5 = n5; a6 = n6; a7 = n7;
    };
    // lossless power-of-two rescale; alphas >= 0 so hi-word int order == value order
    auto rescale = [&]() {
        int h = __double2hiint(a0);
        int h1 = __double2hiint(a1); h = (h1 > h) ? h1 : h;
        h1 = __double2hiint(a2);     h = (h1 > h) ? h1 : h;
        h1 = __double2hiint(a3);     h = (h1 > h) ? h1 : h;
        h1 = __double2hiint(a4);     h = (h1 > h) ? h1 : h;
        h1 = __double2hiint(a5);     h = (h1 > h) ? h1 : h;
        h1 = __double2hiint(a6);     h = (h1 > h) ? h1 : h;
        h1 = __double2hiint(a7);     h = (h1 > h) ? h1 : h;
        #pragma unroll
        for (int o = 1; o < 64; o <<= 1) {
            const int hx = __shfl_xor(h, o, 64);
            h = (hx > h) ? hx : h;
        }
        if (h > 0) {
            const int be_ = h >> 20;             // biased exponent (sign=0)
            const int ex  = be_ - 1022;          // max = f*2^ex, f in [0.5,1)
            const double sf = __hiloint2double((2045 - be_) << 20, 0);  // 2^-ex exact
            a0 *= sf; a1 *= sf; a2 *= sf; a3 *= sf;
            a4 *= sf; a5 *= sf; a6 *= sf; a7 *= sf;
            logscale += (double)ex * 0.6931471805599453;
        }
    };

#define LDROW(dst, rowptr) { const float* _r = (rowptr);                      \
        dst[0] = _r[off0]; dst[1] = _r[off1]; dst[2] = _r[off2];              \
        dst[3] = _r[off3]; dst[4] = _r[CC - 1]; }
#define DOSTEP(src) step(src[0], src[1], src[2], src[3], src[4])

    if (len == TT) {
        // ---------- fast pipelined path (always taken in this benchmark) ----
        float e0[5], e1[5], e2[5], e3[5];
        LDROW(e0, ldsP[0] + 0 * CC);
        LDROW(e1, ldsP[0] + 1 * CC);
        LDROW(e2, ldsP[0] + 2 * CC);
        LDROW(e3, ldsP[0] + 3 * CC);

        for (int c = 0; c < 50; ++c) {
            const int par = c & 1;
            const float* buf = ldsP[par];
            #pragma unroll
            for (int q = 0; q < 9; ++q) {
                const float* r = buf + (q * 4) * CC;
                if (c + q) DOSTEP(e0);           // skip only u=0 of chunk 0
                LDROW(e0, r + 4 * CC);
                DOSTEP(e1); LDROW(e1, r + 5 * CC);
                DOSTEP(e2); LDROW(e2, r + 6 * CC);
                DOSTEP(e3); LDROW(e3, r + 7 * CC);
            }
            if (c < 49) {
                stage_write(par ^ 1);            // vmcnt drain + ds_writes
                if (c < 48) stage_load(c + 2);   // issue next chunk's loads
                const float* nb = ldsP[par ^ 1];
                DOSTEP(e0); LDROW(e0, nb + 0 * CC);
                DOSTEP(e1); LDROW(e1, nb + 1 * CC);
                DOSTEP(e2); LDROW(e2, nb + 2 * CC);
                DOSTEP(e3); LDROW(e3, nb + 3 * CC);
            } else {
                DOSTEP(e0); DOSTEP(e1); DOSTEP(e2); DOSTEP(e3);
            }
            rescale();
        }
    } else {
        // ---------- generic checked path (len < T), non-pipelined -----------
        auto dostep = [&](const float* row) {
            step(row[off0], row[off1], row[off2], row[off3], row[CC - 1]);
        };
        for (int c = 0; c < 50; ++c) {
            const int par = c & 1;
            const float* buf = ldsP[par];
            const int tbase = c * 40;
            const int u0 = (c == 0) ? 1 : 0;
            for (int u = u0; u < 40; ++u)
                if (tbase + u < len) dostep(buf + u * CC);
            rescale();
            if (c < 49) {
                stage_write(par ^ 1);
                if (c < 48) stage_load(c + 2);
            }
        }
    }
#undef LDROW
#undef DOSTEP

    // readout: alpha at states 2*tl and 2*tl-1
    double contrib = 0.0;
    const int send = 2 * tl;
    #pragma unroll
    for (int i = 0; i < 8; ++i) {
        const int s = 8 * l + i;
        const double av = (i == 0) ? a0 : (i == 1) ? a1 : (i == 2) ? a2 :
                          (i == 3) ? a3 : (i == 4) ? a4 : (i == 5) ? a5 :
                          (i == 6) ? a6 : a7;
        if (s == send || s == send - 1) contrib += av;
    }
    #pragma unroll
    for (int o = 32; o > 0; o >>= 1) contrib += __shfl_xor(contrib, o, 64);

    if (l == 0) {
        double lb = 0.0;
        if (contrib > 0.0) lb = -(log(contrib) + logscale);
        if (lb > 1e29) lb = 0.0;                 // zero_infinity
        loss_ws[b] = (float)(lb / (double)tl);
    }
}

// ---------------------------------------------------------------------------
// k3: mean over batches -> final loss scalar.
// ---------------------------------------------------------------------------
__global__ void k3_reduce(const float* __restrict__ ws, float* __restrict__ loss_out)
{
    if (threadIdx.x == 0 && blockIdx.x == 0) {
        float sum = 0.0f;
        #pragma unroll
        for (int b = 0; b < BB; ++b) sum += ws[b];
        *loss_out = sum / (float)BB;
    }
}

// ===========================================================================
// FALLBACK path (round-3, proven): used only if ws_size too small for P.
// ===========================================================================
__global__ __launch_bounds__(256) void k1_lds(
    const float* __restrict__ hidden, const float* __restrict__ W,
    const float* __restrict__ bias, float* __restrict__ out)
{
    __shared__ float Wl[CC * 256];
    float4* Wl4 = (float4*)Wl;
    const int tid = threadIdx.x;
    const int r = blockIdx.x * blockDim.x + tid;
    const float4* __restrict__ h4 = (const float4*)(hidden + (size_t)r * HH);
    const float4* __restrict__ W4g = (const float4*)W;
    float acc[CC];
    #pragma unroll
    for (int c = 0; c < CC; ++c) acc[c] = 0.0f;
    for (int kc = 0; kc < 2; ++kc) {
        __syncthreads();
        #pragma unroll
        for (int i = 0; i < 10; ++i) {
            const int idx = tid + i * 256;
            const int c = idx >> 6, j4 = idx & 63;
            Wl4[idx] = W4g[c * 128 + kc * 64 + j4];
        }
        __syncthreads();
        #pragma unroll 2
        for (int k4 = 0; k4 < 64; ++k4) {
            const float4 h = h4[kc * 64 + k4];
            #pragma unroll
            for (int c = 0; c < CC; ++c) {
                const float4 w = Wl4[c * 64 + k4];
                acc[c] = fmaf(h.x, w.x, fmaf(h.y, w.y,
                         fmaf(h.z, w.z, fmaf(h.w, w.w, acc[c]))));
            }
        }
    }
    #pragma unroll
    for (int c = 0; c < CC; ++c) acc[c] += bias[c];
    float mx = acc[0];
    #pragma unroll
    for (int c = 1; c < CC; ++c) mx = fmaxf(mx, acc[c]);
    float s = 0.0f;
    #pragma unroll
    for (int c = 0; c < CC; ++c) s += __expf(acc[c] - mx);
    const float lse = mx + __logf(s);
    const int b = r / TT, t = r - b * TT;
    float4* __restrict__ o4 = (float4*)(out + ((size_t)t * BB + b) * CC);
    #pragma unroll
    for (int c4 = 0; c4 < CC / 4; ++c4) {
        float4 v;
        v.x = acc[4 * c4 + 0] - lse; v.y = acc[4 * c4 + 1] - lse;
        v.z = acc[4 * c4 + 2] - lse; v.w = acc[4 * c4 + 3] - lse;
        o4[c4] = v;
    }
}

__device__ __forceinline__ float bperm(int byteaddr, float v) {
    return __int_as_float(__builtin_amdgcn_ds_bpermute(byteaddr, __float_as_int(v)));
}

__global__ __launch_bounds__(64) void k2_legacy(
    const float* __restrict__ lp, const int* __restrict__ targets,
    const int* __restrict__ input_lengths, const int* __restrict__ target_lengths,
    float* __restrict__ ws)
{
    const int b = blockIdx.x, lane = threadIdx.x;
    const int len = input_lengths[b];
    const int tl = target_lengths[b];
    const int S = 2 * tl + 1;
    int cad[7]; double skf[7];
    #pragma unroll
    for (int i = 0; i < 7; ++i) {
        const int s = 7 * lane + i;
        int cls = 63; double sk = 0.0;
        if (s < S) {
            if (s & 1) {
                cls = targets[b * LL + (s >> 1)];
                if (s >= 3) sk = (cls != targets[b * LL + ((s - 3) >> 1)]) ? 1.0 : 0.0;
                else sk = 1.0;
            } else cls = CC - 1;
        }
        cad[i] = cls * 4; skf[i] = sk;
    }
    const double lane0m = (lane == 0) ? 0.0 : 1.0;
    const int lc = (lane < CC) ? lane : (CC - 1);
    const size_t rowstride = (size_t)BB * CC;
    const float* lprow = lp + (size_t)b * CC + lc;
    double a0, a1, a2, a3, a4, a5, a6;
    {
        const float v0 = lprow[0];
        const float e = (lane < CC) ? __expf(v0) : 0.0f;
        a0 = (lane == 0) ? (double)bperm(cad[0], e) : 0.0;
        a1 = (lane == 0) ? (double)bperm(cad[1], e) : 0.0;
        a2 = a3 = a4 = a5 = a6 = 0.0;
    }
    float Pr[8];
    #pragma unroll
    for (int u = 0; u < 8; ++u) Pr[u] = lprow[(size_t)(1 + u) * rowstride];
    double logscale = 0.0;
    auto step = [&](int t, float pv) {
        const float ef = (lane < CC) ? __expf(pv) : 0.0f;
        const double e0 = (double)bperm(cad[0], ef), e1 = (double)bperm(cad[1], ef);
        const double e2 = (double)bperm(cad[2], ef), e3 = (double)bperm(cad[3], ef);
        const double e4 = (double)bperm(cad[4], ef), e5 = (double)bperm(cad[5], ef);
        const double e6 = (double)bperm(cad[6], ef);
        const double pl1 = __shfl_up(a6, 1, 64) * lane0m;
        const double pl2 = __shfl_up(a5, 1, 64) * lane0m;
        const double n0 = (a0 + fma(skf[0], pl2, pl1)) * e0;
        const double n1 = (a1 + fma(skf[1], pl1, a0)) * e1;
        const double n2 = (a2 + fma(skf[2], a0, a1)) * e2;
        const double n3 = (a3 + fma(skf[3], a1, a2)) * e3;
        const double n4 = (a4 + fma(skf[4], a2, a3)) * e4;
        const double n5 = (a5 + fma(skf[5], a3, a4)) * e5;
        const double n6 = (a6 + fma(skf[6], a4, a5)) * e6;
        if (t < len) { a0 = n0; a1 = n1; a2 = n2; a3 = n3; a4 = n4; a5 = n5; a6 = n6; }
    };
    auto rescale = [&]() {
        double m = fmax(fmax(fmax(a0, a1), fmax(a2, a3)), fmax(fmax(a4, a5), a6));
        #pragma unroll
        for (int o = 32; o > 0; o >>= 1) m = fmax(m, __shfl_xor(m, o, 64));
        if (m > 0.0) {
            const double inv = 1.0 / m;
            a0 *= inv; a1 *= inv; a2 *= inv; a3 *= inv; a4 *= inv; a5 *= inv; a6 *= inv;
            logscale += (double)__logf((float)m);
        }
    };
    for (int it = 0; it < 249; ++it) {
        const int t = 1 + it * 8, tb = t + 8;
        const float* pf = lprow + (size_t)tb * rowstride;
        float q[8];
        #pragma unroll
        for (int u = 0; u < 8; ++u) q[u] = (tb + u < TT) ? pf[(size_t)u * rowstride] : 0.0f;
        #pragma unroll
        for (int u = 0; u < 8; ++u) step(t + u, Pr[u]);
        rescale();
        #pragma unroll
        for (int u = 0; u < 8; ++u) Pr[u] = q[u];
    }
    #pragma unroll
    for (int u = 0; u < 7; ++u) step(1993 + u, Pr[u]);
    double contrib = 0.0;
    #pragma unroll
    for (int i = 0; i < 7; ++i) {
        const int s = 7 * lane + i;
        const double av = (i == 0) ? a0 : (i == 1) ? a1 : (i == 2) ? a2 :
                          (i == 3) ? a3 : (i == 4) ? a4 : (i == 5) ? a5 : a6;
        if (s == 2 * tl || s == 2 * tl - 1) contrib += av;
    }
    #pragma unroll
    for (int o = 32; o > 0; o >>= 1) contrib += __shfl_xor(contrib, o, 64);
    if (lane == 0) {
        double lb = 0.0;
        if (contrib > 0.0) lb = -(log(contrib) + logscale);
        if (lb > 1e29) lb = 0.0;
        ws[b] = (float)(lb / (double)tl);
    }
}

extern "C" void kernel_launch(void* const* d_in, const int* in_sizes, int n_in,
                              void* d_out, int out_size, void* d_ws, size_t ws_size,
                              hipStream_t stream) {
    const float* hidden = (const float*)d_in[0];
    const float* W      = (const float*)d_in[1];
    const float* bias   = (const float*)d_in[2];
    const int* targets  = (const int*)d_in[3];
    const int* in_len   = (const int*)d_in[4];
    const int* tg_len   = (const int*)d_in[5];

    float* out      = (float*)d_out;
    float* loss_out = out + (size_t)TT * BB * CC;

    const size_t PELEMS   = (size_t)BB * CC * TT;                 // 2,560,000 floats
    const size_t WBF_OFF  = PELEMS;                                // float offset
    const size_t LOSS_OFF = PELEMS + (48 * HH * sizeof(short)) / sizeof(float);
    const size_t need     = (LOSS_OFF + BB) * sizeof(float);       // ~10.3 MB

    if (ws_size >= need) {
        float* P   = (float*)d_ws;                                 // (B,T,C)
        short* wbf = (short*)((float*)d_ws + WBF_OFF);             // (48,H) bf16
        float* lws = (float*)d_ws + LOSS_OFF;                      // (B,)
        k0_wconv<<<dim3(96), dim3(256), 0, stream>>>(W, wbf);
        k1_mfma<<<dim3(1000), dim3(256), 0, stream>>>(hidden, wbf, bias, out, P);
        k2_fast<<<dim3(BB), dim3(64), 0, stream>>>(P, targets, in_len, tg_len, lws);
        k3_reduce<<<dim3(1), dim3(64), 0, stream>>>(lws, loss_out);
    } else {
        float* lws = (float*)d_ws;
        k1_lds<<<dim3((BB * TT) / 256), dim3(256), 0, stream>>>(hidden, W, bias, out);
        k2_legacy<<<dim3(BB), dim3(64), 0, stream>>>(out, targets, in_len, tg_len, lws);
        k3_reduce<<<dim3(1), dim3(64), 0, stream>>>(lws, loss_out);
    }
}